// Round 7
// baseline (910.946 us; speedup 1.0000x reference)
//
#include <hip/hip_runtime.h>
#include <cmath>

constexpr int BN = 4, CN = 128, HN = 256, WN = 256;
constexpr int NPLANE = BN * CN;          // 512
constexpr int PLANE  = HN * WN;          // 65536

// workspace layout (float offsets); end = 39,146,496 floats = 157 MB
constexpr long long OF_THR = 0;                                  // 1024
constexpr long long OF_R1  = 1024;                               // 2*512*128*128
constexpr long long OF_D1  = OF_R1 + 2LL * NPLANE * 128 * 128;
constexpr long long OF_D2  = OF_D1 + 2LL * NPLANE * 128 * 128;
constexpr long long OF_D3  = OF_D2 + 2LL * NPLANE * 64 * 64;
constexpr long long OF_D4  = OF_D3 + 2LL * NPLANE * 32 * 32;
constexpr long long OF_D5  = OF_D4 + 2LL * NPLANE * 16 * 16;
constexpr long long OF_D6  = OF_D5 + 2LL * NPLANE * 8 * 8;
constexpr long long OF_D7  = OF_D6 + 2LL * NPLANE * 4 * 4;
// stats partials are parked in the (not yet written) D1 region.

static __device__ __forceinline__ float sigm100(float a, float thr) {
    return 1.f / (1.f + __expf(-100.f * (a - thr))) + 1e-6f;
}

// --------------------------------------------------------------- statsA ----
// partial sums per (plane, 16-row strip) -> float4 partials in D1 region
__global__ __launch_bounds__(256) void statsA_kernel(const float* __restrict__ x,
                                                     float* __restrict__ ws) {
    const int strip = blockIdx.x;   // 0..15
    const int p = blockIdx.y;       // 0..511
    const int tid = threadIdx.x;
    const float* xp = x + (long long)p * PLANE + strip * 4096;
    float sp = 0, spp = 0, sn = 0, snn = 0;
    for (int i = tid; i < 4096; i += 256) {
        float v = xp[i];
        float a = fmaxf(v, 0.f), b = fmaxf(-v, 0.f);
        sp += a; spp += a * a;
        sn += b; snn += b * b;
    }
    __shared__ float red[256];
    float vals[4] = {sp, spp, sn, snn};
    float* dst = ws + OF_D1 + ((long long)p * 16 + strip) * 4;
    for (int q = 0; q < 4; q++) {
        red[tid] = vals[q];
        __syncthreads();
        for (int s = 128; s > 0; s >>= 1) {
            if (tid < s) red[tid] += red[tid + s];
            __syncthreads();
        }
        if (tid == 0) dst[q] = red[0];
        __syncthreads();
    }
}

// --------------------------------------------------------------- statsB ----
__global__ __launch_bounds__(256) void statsB_kernel(float* __restrict__ ws) {
    int p = blockIdx.x * 256 + threadIdx.x;   // grid 2 x 256 -> 512 planes
    if (p >= 512) return;
    double sp = 0, spp = 0, sn = 0, snn = 0;
    for (int s = 0; s < 16; s++) {
        const float* src = ws + OF_D1 + ((long long)p * 16 + s) * 4;
        sp += src[0]; spp += src[1]; sn += src[2]; snn += src[3];
    }
    double N = (double)PLANE;
    double meanP = sp / N, meanN = sn / N;
    double varP = (spp - sp * sp / N) / (N - 1.0);
    double varN = (snn - sn * sn / N) / (N - 1.0);
    varP = varP > 0 ? varP : 0;
    varN = varN > 0 ? varN : 0;
    ws[OF_THR + p]       = (float)(meanP + 2.0 * sqrt(varP));
    ws[OF_THR + 512 + p] = (float)(meanN + 2.0 * sqrt(varN));
}

// -------------------------------------------------- field -> r1 only ----
// Combined-sign field c = v * sigm(|v|, thr_sign). One block = one 64x64
// tile. The 4 pooled values each resize output needs are computed directly
// from cf with the same 9-point windows / clamps / lerp (bit-identical).
// LDS 17.4 KB => 8 blocks/CU.
#define POOL9(LY, LX, MX, MN)                                                 \
    {   const float* q_ = cf + (LY) * 66 + (LX);                              \
        float t0 = q_[0],   t1 = q_[1],   t2 = q_[2];                         \
        float u0 = q_[66],  u1 = q_[67],  u2 = q_[68];                        \
        float w0 = q_[132], w1 = q_[133], w2 = q_[134];                       \
        MX = fmaxf(fmaxf(fmaxf(t0, t1), t2),                                  \
             fmaxf(fmaxf(fmaxf(u0, u1), u2),                                  \
                   fmaxf(fmaxf(w0, w1), w2)));                                \
        MN = fminf(fminf(fminf(t0, t1), t2),                                  \
             fminf(fminf(fminf(u0, u1), u2),                                  \
                   fminf(fminf(w0, w1), w2))); }

__global__ __launch_bounds__(256, 8) void field_kernel(const float* __restrict__ x,
                                                       float* __restrict__ ws) {
    const int tile = blockIdx.x;           // 0..15  (ty*4+tx)
    const int p = blockIdx.y;              // 0..511
    const int ty = tile >> 2, tx = tile & 3;
    const int y0 = ty * 64, x0 = tx * 64;
    const int tid = threadIdx.x;

    __shared__ float cf[66 * 66];

    const float thrP = ws[OF_THR + p];
    const float thrN = ws[OF_THR + 512 + p];
    const float* xp = x + (long long)p * PLANE;

    for (int i = tid; i < 66 * 66; i += 256) {
        int ly = i / 66, lx = i - ly * 66;
        int gy = min(max(y0 - 1 + ly, 0), 255);
        int gx = min(max(x0 - 1 + lx, 0), 255);
        float v = xp[gy * 256 + gx];
        float thr = v > 0.f ? thrP : thrN;
        cf[i] = v * sigm100(fabsf(v), thr);
    }
    __syncthreads();

    const float g1 = 0.99f;
    const float S = (float)(255.0 / 127.0);
    for (int i = tid; i < 32 * 32; i += 256) {
        int ry = i >> 5, rx = i & 31;
        int jy = ty * 32 + ry, jx = tx * 32 + rx;
        float uy = jy * S, ux = jx * S;
        int iy0 = (int)floorf(uy), ix0 = (int)floorf(ux);
        int iy1 = min(iy0 + 1, 255), ix1 = min(ix0 + 1, 255);
        float fy = uy - iy0, fx = ux - ix0;
        int ly0 = min(max(iy0 - y0, 0), 63), ly1 = min(max(iy1 - y0, 0), 63);
        int lx0 = min(max(ix0 - x0, 0), 63), lx1 = min(max(ix1 - x0, 0), 63);

        float amx, amn, bmx, bmn, cmx, cmn, dmx, dmn;
        POOL9(ly0, lx0, amx, amn)
        POOL9(ly0, lx1, bmx, bmn)
        POOL9(ly1, lx0, cmx, cmn)
        POOL9(ly1, lx1, dmx, dmn)

        float aP = fmaxf(amx, 0.f) * g1, bP = fmaxf(bmx, 0.f) * g1;
        float cP = fmaxf(cmx, 0.f) * g1, dP = fmaxf(dmx, 0.f) * g1;
        float vP = (aP * (1.f - fy) + cP * fy) * (1.f - fx) + (bP * (1.f - fy) + dP * fy) * fx;
        float aN = fmaxf(-amn, 0.f) * g1, bN = fmaxf(-bmn, 0.f) * g1;
        float cN = fmaxf(-cmn, 0.f) * g1, dN = fmaxf(-dmn, 0.f) * g1;
        float vN = (aN * (1.f - fy) + cN * fy) * (1.f - fx) + (bN * (1.f - fy) + dN * fy) * fx;
        ws[OF_R1 + (long long)p * 16384 + jy * 128 + jx] = vP;
        ws[OF_R1 + (long long)(512 + p) * 16384 + jy * 128 + jx] = vN;
    }
}

// ---------------------------------------------------------------- pool1 ----
// Split back out of the fused pyramid. The level-1 bulk (16.7M outputs)
// runs at full occupancy (65536 blocks, no LDS) instead of the fused
// kernel's 2 blocks/CU (80 KB LDS).
__global__ __launch_bounds__(256) void pool1_kernel(float* __restrict__ ws, float gamma2) {
    long long gid = (long long)blockIdx.x * 256 + threadIdx.x;
    int ps = (int)(gid >> 14);
    int rem = (int)(gid & 16383);
    int oy = rem >> 7, ox = rem & 127;
    const float* src = ws + OF_R1 + (long long)ps * 16384;
    float m = -INFINITY;
    for (int dy = -1; dy <= 1; dy++) {
        int yy = oy + dy;
        if (yy < 0 || yy > 127) continue;
        for (int dx = -1; dx <= 1; dx++) {
            int xx = ox + dx;
            if (xx < 0 || xx > 127) continue;
            m = fmaxf(m, src[yy * 128 + xx]);
        }
    }
    ws[OF_D1 + (long long)ps * 16384 + rem] = m * gamma2;
}

// --------------------------------------------------------- pyramid rest ----
// Levels 2..7 for one sign-plane per block. Level 2 reads D1 from GLOBAL
// (written by the pool1 launch -> cross-launch visibility is safe; 64 KB
// per plane, L2-hot). Levels 3..7 ping-pong through small LDS (A 16 KB /
// B 4 KB). Math identical to the old pstep chain; gammas by double
// repeated squaring (== std::pow to the ulp for these arguments).
__global__ __launch_bounds__(256) void pyramid_rest_kernel(float* __restrict__ ws) {
    const int ps = blockIdx.x;        // 0..1023 (sign*512 + plane)
    const int tid = threadIdx.x;
    __shared__ float A[4096];
    __shared__ float B[1024];

    const long long OFD[8] = {0, OF_D1, OF_D2, OF_D3, OF_D4, OF_D5, OF_D6, OF_D7};
    double gd = 0.99 * 0.99;

    // ---- level 2: read D1 (global), write D2 (global) + A (LDS) ----
    {
        const int m = 128, n = 64, logn = 6;
        gd = gd * gd;                                   // 0.99^4
        const float gamma = (float)gd;
        const float scale = (float)(127.0 / 63.0);
        const float* src = ws + OF_D1 + (long long)ps * 16384;
        float* dst = ws + OF_D2 + (long long)ps * n * n;
        for (int i = tid; i < n * n; i += 256) {
            int oy = i >> logn, ox = i & (n - 1);
            float best = -INFINITY;
            for (int dy = -1; dy <= 1; dy++) {
                int yy = oy + dy;
                if (yy < 0 || yy >= n) continue;
                float uy = yy * scale;
                int iy0 = (int)floorf(uy);
                if (iy0 > m - 1) iy0 = m - 1;
                int iy1 = min(iy0 + 1, m - 1);
                float fy = uy - iy0;
                for (int dx = -1; dx <= 1; dx++) {
                    int xx = ox + dx;
                    if (xx < 0 || xx >= n) continue;
                    float ux = xx * scale;
                    int ix0 = (int)floorf(ux);
                    if (ix0 > m - 1) ix0 = m - 1;
                    int ix1 = min(ix0 + 1, m - 1);
                    float fx = ux - ix0;
                    float a = src[iy0 * m + ix0], b = src[iy0 * m + ix1];
                    float c = src[iy1 * m + ix0], d = src[iy1 * m + ix1];
                    float v = (a * (1.f - fy) + c * fy) * (1.f - fx) + (b * (1.f - fy) + d * fy) * fx;
                    best = fmaxf(best, v);
                }
            }
            float o = best * gamma;
            dst[i] = o; A[i] = o;
        }
    }
    __syncthreads();

    // ---- levels 3..7 from LDS ----
    float* curL = A;
    float* nxtL = B;
#pragma unroll
    for (int k = 3; k <= 7; k++) {
        const int m = 256 >> (k - 1), n = 256 >> k;
        const int logn = 8 - k;
        gd = gd * gd;                                   // 0.99^(2^k)
        const float gamma = (float)gd;
        const float scale = (float)((double)(m - 1) / (double)(n - 1));
        float* dst = ws + OFD[k] + (long long)ps * n * n;
        for (int i = tid; i < n * n; i += 256) {
            int oy = i >> logn, ox = i & (n - 1);
            float best = -INFINITY;
            for (int dy = -1; dy <= 1; dy++) {
                int yy = oy + dy;
                if (yy < 0 || yy >= n) continue;
                float uy = yy * scale;
                int iy0 = (int)floorf(uy);
                if (iy0 > m - 1) iy0 = m - 1;
                int iy1 = min(iy0 + 1, m - 1);
                float fy = uy - iy0;
                for (int dx = -1; dx <= 1; dx++) {
                    int xx = ox + dx;
                    if (xx < 0 || xx >= n) continue;
                    float ux = xx * scale;
                    int ix0 = (int)floorf(ux);
                    if (ix0 > m - 1) ix0 = m - 1;
                    int ix1 = min(ix0 + 1, m - 1);
                    float fx = ux - ix0;
                    float a = curL[iy0 * m + ix0], b = curL[iy0 * m + ix1];
                    float c = curL[iy1 * m + ix0], d = curL[iy1 * m + ix1];
                    float v = (a * (1.f - fy) + c * fy) * (1.f - fx) + (b * (1.f - fy) + d * fy) * fx;
                    best = fmaxf(best, v);
                }
            }
            float o = best * gamma;
            dst[i] = o; nxtL[i] = o;
        }
        __syncthreads();
        float* t = curL; curL = nxtL; nxtL = t;
    }
}

// ------------------------------------------------------------- radiance ----
// Round-0's proven barrier-free fully-LDS-staged structure with QBLK=8 row
// tiles (was 16). Halving the tile shrinks BOTH LDS consumers: cf 10x258
// (10.3 KB) and the full per-tile pyramid footprint incl level 1 (<=1210
// floats/sign, 9.7 KB). Total ~19.6 KB => 8 blocks/CU cap (was 4 at round
// 0; round 5's in-loop ring barriers regressed). (256,4) is the proven
// no-spill launch bound (min-waves>=6 made the scheduler spill, r2-r4).
constexpr int QBLK = 8;
constexpr int FPW  = 1216;   // floats per sign; exact max = 1210

__global__ __launch_bounds__(256, 4) void radiance_kernel(const float* __restrict__ x,
                                                          const float* __restrict__ ws,
                                                          float* __restrict__ rad) {
    const int tY = blockIdx.x;     // 0..31
    const int p = blockIdx.y;      // 0..511
    const int Y0 = tY * QBLK;
    const int tid = threadIdx.x;   // = column

    __shared__ float cf[(QBLK + 2) * 258];   // field rows Y0-1..Y0+QBLK (clamped)
    __shared__ float fpb[2 * FPW];           // pyramid footprints, both signs

    const float thrP = ws[OF_THR + p];
    const float thrN = ws[OF_THR + 512 + p];
    const float* xp = x + (long long)p * PLANE;

    // stage combined field; cols duplicated at 0 and 257 (clamp trick)
    for (int r = 0; r < QBLK + 2; r++) {
        int gy = min(max(Y0 - 1 + r, 0), 255);
        float v = xp[gy * 256 + tid];
        float thr = v > 0.f ? thrP : thrN;
        float c = v * sigm100(fabsf(v), thr);
        cf[r * 258 + tid + 1] = c;
        if (tid == 0) cf[r * 258] = c;
        if (tid == 255) cf[r * 258 + 257] = c;
    }

    // footprint extents k=1..7
    int oyk[8], hyk[8], basek[8];
    int acc = 0;
#pragma unroll
    for (int k = 1; k <= 7; k++) {
        int n = 256 >> k;
        float sc = (float)(n - 1) / 255.f;
        int oy = (int)floorf(Y0 * sc);
        int ey = (int)floorf((Y0 + QBLK - 1) * sc) + 1;
        if (ey > n - 1) ey = n - 1;
        oyk[k] = oy; hyk[k] = ey - oy + 1; basek[k] = acc;
        acc += hyk[k] * n;
    }
    const long long OFD[8] = {0, OF_D1, OF_D2, OF_D3, OF_D4, OF_D5, OF_D6, OF_D7};
    for (int s = 0; s < 2; s++) {
#pragma unroll
        for (int k = 1; k <= 7; k++) {
            int n = 256 >> k;
            const float* src = ws + OFD[k] + (long long)(s * 512 + p) * n * n + oyk[k] * n;
            float* dst = fpb + s * FPW + basek[k];
            int tot = hyk[k] * n;
            for (int i = tid; i < tot; i += 256) dst[i] = src[i];
        }
    }
    __syncthreads();

    // per-thread per-level x-lerp constants
    int j0[8], j1[8]; float fxk[8];
#pragma unroll
    for (int k = 1; k <= 7; k++) {
        int n = 256 >> k;
        float sc = (float)(n - 1) / 255.f;
        float ux = tid * sc;
        int a = (int)ux; if (a > n - 1) a = n - 1;
        j0[k] = a; j1[k] = min(a + 1, n - 1);
        fxk[k] = ux - (float)a;
    }

    // register cache: x-lerped footprint rows iy0 (xl0) and iy1 (xl1)
    float xl0P[8], xl1P[8], xl0N[8], xl1N[8];
    int cy[8];
#pragma unroll
    for (int k = 1; k <= 7; k++) {
        int n = 256 >> k;
        int i0 = oyk[k];
        int i1 = min(i0 + 1, n - 1);
        cy[k] = i0;
        int r1o = (i1 - oyk[k]) * n;
        float aP = fpb[basek[k] + j0[k]],        bP = fpb[basek[k] + j1[k]];
        float cP = fpb[basek[k] + r1o + j0[k]],  dP = fpb[basek[k] + r1o + j1[k]];
        xl0P[k] = aP + fxk[k] * (bP - aP);
        xl1P[k] = cP + fxk[k] * (dP - cP);
        float aN = fpb[FPW + basek[k] + j0[k]],       bN = fpb[FPW + basek[k] + j1[k]];
        float cN = fpb[FPW + basek[k] + r1o + j0[k]], dN = fpb[FPW + basek[k] + r1o + j1[k]];
        xl0N[k] = aN + fxk[k] * (bN - aN);
        xl1N[k] = cN + fxk[k] * (dN - cN);
    }

    // level-0 streaming rings (rows lr-1, lr, lr+1)
    float hx0, hx1, hx2, hn0, hn1, hn2, cc1, cc2;
    {
        int b0 = 0 * 258 + tid;
        float a = cf[b0], b = cf[b0 + 1], c = cf[b0 + 2];
        hx0 = fmaxf(fmaxf(a, b), c); hn0 = fminf(fminf(a, b), c);
        int b1 = 1 * 258 + tid;
        float d = cf[b1], e = cf[b1 + 1], f = cf[b1 + 2];
        hx1 = fmaxf(fmaxf(d, e), f); hn1 = fminf(fminf(d, e), f);
        cc1 = e;
    }

    float* radp = rad + (long long)p * PLANE + (long long)Y0 * 256 + tid;

    for (int q = 0; q < QBLK; q++) {
        // next field row (lr+1 = q+2)
        int bn = (q + 2) * 258 + tid;
        float a = cf[bn], b = cf[bn + 1], c = cf[bn + 2];
        hx2 = fmaxf(fmaxf(a, b), c); hn2 = fminf(fminf(a, b), c);
        cc2 = b;

        float poolmax = fmaxf(fmaxf(hx0, hx1), hx2);
        float poolmin = fminf(fminf(hn0, hn1), hn2);
        float mP = fmaxf(fmaxf(cc1, 0.f), 0.99f * fmaxf(poolmax, 0.f));
        float mN = fmaxf(fmaxf(-cc1, 0.f), 0.99f * fmaxf(-poolmin, 0.f));

        int row = Y0 + q;
#pragma unroll
        for (int k = 1; k <= 7; k++) {
            int n = 256 >> k;
            float sc = (float)(n - 1) / 255.f;
            float uy = row * sc;
            int i0 = (int)uy;
            if (i0 != cy[k]) {           // wave-uniform advance (by exactly 1)
                cy[k] = i0;
                xl0P[k] = xl1P[k]; xl0N[k] = xl1N[k];
                int i1 = min(i0 + 1, n - 1);
                int ro = (i1 - oyk[k]) * n;
                float aP = fpb[basek[k] + ro + j0[k]], bP = fpb[basek[k] + ro + j1[k]];
                xl1P[k] = aP + fxk[k] * (bP - aP);
                float aN = fpb[FPW + basek[k] + ro + j0[k]], bN = fpb[FPW + basek[k] + ro + j1[k]];
                xl1N[k] = aN + fxk[k] * (bN - aN);
            }
            float fy = uy - (float)i0;
            mP = fmaxf(mP, xl0P[k] + fy * (xl1P[k] - xl0P[k]));
            mN = fmaxf(mN, xl0N[k] + fy * (xl1N[k] - xl0N[k]));
        }
        radp[q * 256] = mP - mN;

        hx0 = hx1; hx1 = hx2;
        hn0 = hn1; hn1 = hn2;
        cc1 = cc2;
    }
}

// ------------------------------------------------------------------ mlp ----
// io holds rad on entry, final output on exit (per-thread read set == write
// set; all reads precede all writes within a thread).
__global__ __launch_bounds__(256) void mlp_kernel(const float* __restrict__ x,
                                                  const float* __restrict__ w1,
                                                  const float* __restrict__ b1,
                                                  const float* __restrict__ w2,
                                                  const float* __restrict__ b2,
                                                  float* io) {
    const int y = blockIdx.x;   // 0..255
    const int b = blockIdx.y;   // 0..3
    const int col = threadIdx.x;

    float h[16];
#pragma unroll
    for (int o = 0; o < 16; o++) h[o] = b1[o];
    for (int c = 0; c < 128; c++) {
        float r = io[(long long)(b * 128 + c) * PLANE + y * 256 + col];
#pragma unroll
        for (int o = 0; o < 16; o++) h[o] += w1[o * 128 + c] * r;
    }
#pragma unroll
    for (int o = 0; o < 16; o++) h[o] = fmaxf(h[o], 0.f);
    for (int c = 0; c < 128; c++) {
        float z = b2[c];
#pragma unroll
        for (int o = 0; o < 16; o++) z += w2[c * 16 + o] * h[o];
        float mod = 1.f / (1.f + __expf(-z));
        long long idx = (long long)(b * 128 + c) * PLANE + y * 256 + col;
        io[idx] = x[idx] * mod;
    }
}

// -------------------------------------------------------------- launcher ----
extern "C" void kernel_launch(void* const* d_in, const int* in_sizes, int n_in,
                              void* d_out, int out_size, void* d_ws, size_t ws_size,
                              hipStream_t stream) {
    (void)in_sizes; (void)n_in; (void)out_size; (void)ws_size;
    const float* x  = (const float*)d_in[0];
    const float* w1 = (const float*)d_in[1];
    const float* b1 = (const float*)d_in[2];
    const float* w2 = (const float*)d_in[3];
    const float* b2 = (const float*)d_in[4];
    float* out = (float*)d_out;
    float* ws = (float*)d_ws;

    statsA_kernel<<<dim3(16, 512), 256, 0, stream>>>(x, ws);
    statsB_kernel<<<2, 256, 0, stream>>>(ws);
    field_kernel<<<dim3(16, 512), 256, 0, stream>>>(x, ws);
    pool1_kernel<<<(1024 * 16384) / 256, 256, 0, stream>>>(ws, (float)std::pow(0.99, 2.0));
    pyramid_rest_kernel<<<1024, 256, 0, stream>>>(ws);
    radiance_kernel<<<dim3(32, 512), 256, 0, stream>>>(x, ws, out);
    mlp_kernel<<<dim3(256, 4), 256, 0, stream>>>(x, w1, b1, w2, b2, out);
}